// Round 11
// baseline (73.299 us; speedup 1.0000x reference)
//
#include <hip/hip_runtime.h>
#include <math.h>

#define HW    4096
#define NC    32
#define NB    8
#define TINV  10.0f            // 1/TEMP
#define RWIN  8                // window radius; missed sources need |of|>5.5
#define WDIM  (8 + 2 * RWIN)   // 24
#define RCUT  2.5f             // rect cut; excluded normalized weight < 1e-7

typedef __attribute__((ext_vector_type(8))) short short8;  // 8 bf16 (4 VGPRs)
typedef __attribute__((ext_vector_type(4))) float f32x4;   // MFMA acc

__device__ __forceinline__ unsigned short bf16rtn(float f) {
    unsigned int u = __float_as_uint(f);   // f >= 0 finite here, no NaN path
    return (unsigned short)((u + 0x7FFFu + ((u >> 16) & 1u)) >> 16);
}

// ws layout: params (float4 per b*HW) then xt (transposed x, [b][j][c])

__global__ __launch_bounds__(256) void prep_kernel(
    const float* __restrict__ x, const float* __restrict__ of,
    float4* __restrict__ params, float* __restrict__ xt)
{
    __shared__ float tile[32][257];
    int b  = blockIdx.x >> 4;
    int j0 = (blockIdx.x & 15) << 8;
    int t  = threadIdx.x;
    int j  = j0 + t;

    float oy = (float)(j >> 6) + of[(b * 2 + 0) * HW + j];
    float ox = (float)(j & 63) + of[(b * 2 + 1) * HW + j];

    // truncated denominators: omitted terms < e^-25 relative
    int cy0 = min(max((int)floorf(oy), 0), 63);
    int cx0 = min(max((int)floorf(ox), 0), 63);
    float Dy = 0.f, Dx = 0.f;
    #pragma unroll
    for (int d = -3; d <= 3; ++d) {
        int iy = cy0 + d, ix = cx0 + d;
        if ((unsigned)iy < 64u) Dy += __expf(-TINV * fabsf(oy - (float)iy));
        if ((unsigned)ix < 64u) Dx += __expf(-TINV * fabsf(ox - (float)ix));
    }
    params[(b << 12) + j] = make_float4(oy, ox, 1.f / Dy, 1.f / Dx);

    #pragma unroll
    for (int c = 0; c < NC; ++c)
        tile[c][t] = x[((b * NC + c) << 12) + j];
    __syncthreads();
    #pragma unroll
    for (int k = 0; k < NC; ++k) {
        int o  = k * 256 + t;
        int jj = o >> 5, c = o & 31;
        xt[((size_t)((b << 12) + j0 + jj)) * NC + c] = tile[c][jj];
    }
}

// grid: (64 tiles, 2 channel-halves, 8 batches); 16 channels per block.
// Per wave: C[64t x 16c] += W[64t x K] * X[K x 16c] via mfma_f32_16x16x32_bf16
// (M-tiles 4, N-tile 1, K = survivors padded to 32).
__global__ __launch_bounds__(256) void gather_kernel(
    const float4* __restrict__ params, const float4* __restrict__ xt4,
    float* __restrict__ out)
{
    __shared__ float          wpf[4][64 * 5];   // survivor params, stride 5
    __shared__ int            sjl[4][64];       // survivor source idx
    __shared__ unsigned short XS[4][16][66];    // bf16 X[ch][k], row 66 (33 b32)
    __shared__ float          red[4 * 64 * 17]; // cross-wave reduction

    const int b    = blockIdx.z;
    const int h    = blockIdx.y;                // channel half
    const int tile = blockIdx.x;
    const int ty0  = (tile >> 3) << 3;
    const int tx0  = (tile & 7) << 3;

    const int tid  = threadIdx.x;
    const int lane = tid & 63;
    const int wv   = __builtin_amdgcn_readfirstlane(tid >> 6);

    const int   L   = lane & 15;
    const float ixl = (float)(tx0 + (L & 7));   // lane's target x (A rows)
    const float iy0 = (float)(ty0 + (L >> 3));  // base y; M-tile mt adds 2*mt

    f32x4 acc[4];
    #pragma unroll
    for (int mt = 0; mt < 4; ++mt) acc[mt] = (f32x4){0.f, 0.f, 0.f, 0.f};

    const float4* pb = params + (b << 12);
    const float4* xb = xt4 + (size_t)(b << 12) * 8 + h * 4;  // 16 ch @ half h

    const int srow = lane >> 5;                 // screening: 2 rows x 32 cols
    const int scol = lane & 31;

    for (int r = 0; r < 3; ++r) {
        // ---- screen 64 candidates (rows wv+4*srow+8r of 24x24 window) ----
        int ry = wv + srow * 4 + r * 8;
        int jy = ty0 - RWIN + ry;
        int jx = tx0 - RWIN + scol;
        bool valid = ((unsigned)jy < 64u) && ((unsigned)jx < 64u) && (scol < WDIM);
        int j = (jy << 6) + jx;
        float4 p = pb[valid ? j : 0];
        float cy = fminf(fmaxf(p.x, 0.f), 63.f);
        float cx = fminf(fmaxf(p.y, 0.f), 63.f);
        float dyr = fmaxf(fmaxf((float)ty0 - cy, cy - ((float)ty0 + 7.f)), 0.f);
        float dxr = fmaxf(fmaxf((float)tx0 - cx, cx - ((float)tx0 + 7.f)), 0.f);
        bool pred = valid && (dyr + dxr < RCUT);

        unsigned long long m = __ballot(pred);
        int cnt = __popcll(m);                  // wave-uniform
        if (pred) {
            int pos = __builtin_amdgcn_mbcnt_hi((unsigned)(m >> 32),
                      __builtin_amdgcn_mbcnt_lo((unsigned)m, 0u));
            float* wq = &wpf[wv][pos * 5];
            wq[0] = p.x; wq[1] = p.y; wq[2] = p.z; wq[3] = p.w;
            sjl[wv][pos] = j;
        }
        if (cnt == 0) continue;

        // ---- zero this wave's XS slab (pad slots must be 0, not garbage) ----
        unsigned int* xz = (unsigned int*)&XS[wv][0][0];   // 528 dwords
        #pragma unroll
        for (int i = 0; i < 9; ++i) {
            int idx = lane + (i << 6);
            if (idx < 528) xz[idx] = 0u;
        }

        // ---- stage survivors' x as bf16 into XS[ch][k] (16 surv/pass) ----
        for (int base = 0; base < cnt; base += 16) {
            int s = base + (lane >> 2);
            if (s < cnt) {
                int jj = sjl[wv][s];
                float4 v = xb[jj * 8 + (lane & 3)];
                int c0 = (lane & 3) << 2;
                XS[wv][c0 + 0][s] = bf16rtn(v.x);
                XS[wv][c0 + 1][s] = bf16rtn(v.y);
                XS[wv][c0 + 2][s] = bf16rtn(v.z);
                XS[wv][c0 + 3][s] = bf16rtn(v.w);
            }
        }

        // ---- MFMA over K = cnt (padded to 32) ----
        int ksteps = (cnt + 31) >> 5;
        int kchunk = (lane >> 4) << 3;          // this lane's 8-k slice
        for (int ks = 0; ks < ksteps; ++ks) {
            int kbase = (ks << 5) + kchunk;

            // A-frags in registers: A[m = L + 16*mt][k = kbase + j]
            short8 av[4];
            #pragma unroll
            for (int jj8 = 0; jj8 < 8; ++jj8) {
                int k  = kbase + jj8;
                int kc = min(k, cnt - 1);
                const float* pp = &wpf[wv][kc * 5];
                float wx = __expf(-TINV * fabsf(pp[1] - ixl)) * pp[3];
                bool real = (k < cnt);
                #pragma unroll
                for (int mt = 0; mt < 4; ++mt) {
                    // per-dim normalize before product (OOB overflow safety)
                    float wy = __expf(-TINV * fabsf(pp[0] - (iy0 + 2.f * mt)))
                             * pp[2];
                    float w  = wy * wx;
                    av[mt][jj8] = real ? (short)bf16rtn(w) : (short)0;
                }
            }

            // B-frag: B[k = kbase + j][n = L] from XS[L][kbase..kbase+7]
            union { unsigned int u[4]; short8 v; } bu;
            const unsigned int* xr = (const unsigned int*)&XS[wv][L][kbase];
            bu.u[0] = xr[0]; bu.u[1] = xr[1]; bu.u[2] = xr[2]; bu.u[3] = xr[3];

            #pragma unroll
            for (int mt = 0; mt < 4; ++mt)
                acc[mt] = __builtin_amdgcn_mfma_f32_16x16x32_bf16(
                              av[mt], bu.v, acc[mt], 0, 0, 0);
        }
    }

    // ---- cross-wave reduction: D row=(lane>>4)*4+reg (target), col=L (ch) ----
    __syncthreads();
    #pragma unroll
    for (int mt = 0; mt < 4; ++mt) {
        #pragma unroll
        for (int rr = 0; rr < 4; ++rr) {
            int t = (mt << 4) + ((lane >> 4) << 2) + rr;
            red[((wv << 6) + t) * 17 + L] = acc[mt][rr];
        }
    }
    __syncthreads();

    int c   = tid >> 4;                         // 0..15
    int t16 = tid & 15;
    #pragma unroll
    for (int k = 0; k < 4; ++k) {
        int t = t16 + 16 * k;
        float s = red[(0 * 64 + t) * 17 + c]
                + red[(1 * 64 + t) * 17 + c]
                + red[(2 * 64 + t) * 17 + c]
                + red[(3 * 64 + t) * 17 + c];
        int ch = h * 16 + c;
        out[(((b << 5) + ch) << 12) + (ty0 + (t >> 3)) * 64 + (tx0 + (t & 7))] = s;
    }
}

extern "C" void kernel_launch(void* const* d_in, const int* in_sizes, int n_in,
                              void* d_out, int out_size, void* d_ws, size_t ws_size,
                              hipStream_t stream) {
    const float* x  = (const float*)d_in[0];   // [8,32,64,64]
    const float* of = (const float*)d_in[1];   // [8,2,64,64]
    float* out = (float*)d_out;                // [8,32,64,64] fp32

    float4* params = (float4*)d_ws;                                    // 512 KB
    float*  xt     = (float*)((char*)d_ws + NB * HW * sizeof(float4)); // 4 MB

    prep_kernel<<<dim3(NB * 16), dim3(256), 0, stream>>>(x, of, params, xt);
    gather_kernel<<<dim3(64, 2, NB), dim3(256), 0, stream>>>(params, (const float4*)xt, out);
}

// Round 12
// 70.765 us; speedup vs baseline: 1.0358x; 1.0358x over previous
//
#include <hip/hip_runtime.h>
#include <math.h>

#define HW    4096
#define NC    32
#define NB    8
#define TINV  10.0f            // 1/TEMP
#define RWIN  8                // window radius; missed sources need |of|>5.5
#define WDIM  (8 + 2 * RWIN)   // 24
#define RCUT  2.0f             // rect cut; excluded weight <= e^-10/src (~4e-3 total)

// ws layout: params (float4 per b*HW) then xt (transposed x, [b][j][c])

// grid (NB*16, 2): y half 0 -> params + transpose ch 0-15; y=1 -> ch 16-31
__global__ __launch_bounds__(256) void prep_kernel(
    const float* __restrict__ x, const float* __restrict__ of,
    float4* __restrict__ params, float* __restrict__ xt)
{
    __shared__ float tile[16][257];
    int bx   = blockIdx.x;
    int half = blockIdx.y;
    int b    = bx >> 4;
    int j0   = (bx & 15) << 8;
    int t    = threadIdx.x;
    int j    = j0 + t;
    int ch0  = half << 4;

    if (half == 0) {
        float oy = (float)(j >> 6) + of[(b * 2 + 0) * HW + j];
        float ox = (float)(j & 63) + of[(b * 2 + 1) * HW + j];
        // truncated denominators: omitted terms < e^-25 relative
        int cy0 = min(max((int)floorf(oy), 0), 63);
        int cx0 = min(max((int)floorf(ox), 0), 63);
        float Dy = 0.f, Dx = 0.f;
        #pragma unroll
        for (int d = -3; d <= 3; ++d) {
            int iy = cy0 + d, ix = cx0 + d;
            if ((unsigned)iy < 64u) Dy += __expf(-TINV * fabsf(oy - (float)iy));
            if ((unsigned)ix < 64u) Dx += __expf(-TINV * fabsf(ox - (float)ix));
        }
        params[(b << 12) + j] = make_float4(oy, ox, 1.f / Dy, 1.f / Dx);
    }

    // 16-channel half-transpose; both global sides 64 B-aligned coalesced
    #pragma unroll
    for (int c = 0; c < 16; ++c)
        tile[c][t] = x[((b * NC + ch0 + c) << 12) + j];
    __syncthreads();
    #pragma unroll
    for (int k = 0; k < 16; ++k) {
        int o  = k * 256 + t;
        int jj = o >> 4, c = o & 15;
        xt[((size_t)((b << 12) + j0 + jj)) * NC + ch0 + c] = tile[c][jj];
    }
}

// grid: (64 tiles, 2 channel-halves, 8 batches); 16 channels per block
__global__ __launch_bounds__(256) void gather_kernel(
    const float4* __restrict__ params, const float4* __restrict__ xt4,
    float* __restrict__ out)
{
    __shared__ float4 wp[4][64];          //  4 KB  survivor params
    __shared__ int    sj[4][64];          //  1 KB  survivor source idx
    __shared__ float  pool[4 * 64 * 17];  // 17 KB: XS (staging) then red

    const int b    = blockIdx.z;
    const int h    = blockIdx.y;          // channel half
    const int tile = blockIdx.x;
    const int ty0  = (tile >> 3) << 3;
    const int tx0  = (tile & 7) << 3;

    const int tid  = threadIdx.x;
    const int lane = tid & 63;
    const int wv   = __builtin_amdgcn_readfirstlane(tid >> 6);

    const float iy = (float)(ty0 + (lane >> 3));
    const float ix = (float)(tx0 + (lane & 7));

    float acc[16];
    #pragma unroll
    for (int c = 0; c < 16; ++c) acc[c] = 0.f;

    const float4* pb = params + (b << 12);
    const float4* xb = xt4 + (size_t)(b << 12) * 8 + h * 4;  // 16 ch @ half h

    const int srow = lane >> 5;           // 2 window rows x 32 cols per round
    const int scol = lane & 31;
    const int sidq = lane >> 2;           // staging: survivor id (0..15)
    const int quad = lane & 3;            // staging: float4 quad within 64 B

    float* XS = pool;                     // [wv][s][16] floats, stride 16

    for (int r = 0; r < 3; ++r) {
        // ---- screen 64 candidates ----
        int ry = wv + srow * 4 + r * 8;   // all 24 rows over 4 waves
        int jy = ty0 - RWIN + ry;
        int jx = tx0 - RWIN + scol;
        bool valid = ((unsigned)jy < 64u) && ((unsigned)jx < 64u) && (scol < WDIM);
        int j = (jy << 6) + jx;
        float4 p = pb[valid ? j : 0];
        float cy = fminf(fmaxf(p.x, 0.f), 63.f);
        float cx = fminf(fmaxf(p.y, 0.f), 63.f);
        float dyr = fmaxf(fmaxf((float)ty0 - cy, cy - ((float)ty0 + 7.f)), 0.f);
        float dxr = fmaxf(fmaxf((float)tx0 - cx, cx - ((float)tx0 + 7.f)), 0.f);
        bool pred = valid && (dyr + dxr < RCUT);

        unsigned long long m = __ballot(pred);
        int cnt = __popcll(m);
        if (pred) {
            int pos = __builtin_amdgcn_mbcnt_hi((unsigned)(m >> 32),
                      __builtin_amdgcn_mbcnt_lo((unsigned)m, 0u));
            wp[wv][pos] = p;
            sj[wv][pos] = j;
        }

        // ---- stage survivors' x into LDS: lane-parallel, 16 surv/pass ----
        for (int m4 = 0; m4 < cnt; m4 += 16) {
            int s = sidq + m4;
            if (s < cnt) {
                int jj = sj[wv][s];       // 4-lane groups same addr: broadcast
                float4 v = xb[jj * 8 + quad];
                *(float4*)&XS[((wv << 6) + s) * 16 + (quad << 2)] = v;
            }
        }

        // ---- FMA over survivors, 2-wide, all operands from LDS ----
        for (int k = 0; k < cnt; k += 2) {
            int i1 = min(k + 1, cnt - 1);
            float4 p0 = wp[wv][k], p1 = wp[wv][i1];
            const float* x0 = &XS[((wv << 6) + k)  * 16];
            const float* x1 = &XS[((wv << 6) + i1) * 16];
            float4 A[4], B[4];
            #pragma unroll
            for (int u = 0; u < 4; ++u) A[u] = ((const float4*)x0)[u];
            #pragma unroll
            for (int u = 0; u < 4; ++u) B[u] = ((const float4*)x1)[u];

            // per-dim normalize before product (fp32 overflow safety for OOB)
            float g0 = (__expf(-TINV * fabsf(p0.x - iy)) * p0.z)
                     * (__expf(-TINV * fabsf(p0.y - ix)) * p0.w);
            float g1 = (__expf(-TINV * fabsf(p1.x - iy)) * p1.z)
                     * (__expf(-TINV * fabsf(p1.y - ix)) * p1.w);
            g1 = (k + 1 < cnt) ? g1 : 0.f;

            #pragma unroll
            for (int u = 0; u < 4; ++u) {
                acc[4*u+0] = fmaf(g0, A[u].x, acc[4*u+0]);
                acc[4*u+1] = fmaf(g0, A[u].y, acc[4*u+1]);
                acc[4*u+2] = fmaf(g0, A[u].z, acc[4*u+2]);
                acc[4*u+3] = fmaf(g0, A[u].w, acc[4*u+3]);
            }
            #pragma unroll
            for (int u = 0; u < 4; ++u) {
                acc[4*u+0] = fmaf(g1, B[u].x, acc[4*u+0]);
                acc[4*u+1] = fmaf(g1, B[u].y, acc[4*u+1]);
                acc[4*u+2] = fmaf(g1, B[u].z, acc[4*u+2]);
                acc[4*u+3] = fmaf(g1, B[u].w, acc[4*u+3]);
            }
        }
    }

    // ---- cross-wave reduction; red overlays XS (all XS reads done) ----
    __syncthreads();
    float* red = pool;                    // stride 17 -> at most 2-way = free
    float* myred = red + ((wv << 6) + lane) * 17;
    #pragma unroll
    for (int c = 0; c < 16; ++c) myred[c] = acc[c];
    __syncthreads();

    int c   = tid >> 4;                   // 0..15
    int t16 = tid & 15;
    #pragma unroll
    for (int k = 0; k < 4; ++k) {
        int t = t16 + 16 * k;
        float s = red[(0 * 64 + t) * 17 + c]
                + red[(1 * 64 + t) * 17 + c]
                + red[(2 * 64 + t) * 17 + c]
                + red[(3 * 64 + t) * 17 + c];
        int ch = h * 16 + c;
        out[(((b << 5) + ch) << 12) + (ty0 + (t >> 3)) * 64 + (tx0 + (t & 7))] = s;
    }
}

extern "C" void kernel_launch(void* const* d_in, const int* in_sizes, int n_in,
                              void* d_out, int out_size, void* d_ws, size_t ws_size,
                              hipStream_t stream) {
    const float* x  = (const float*)d_in[0];   // [8,32,64,64]
    const float* of = (const float*)d_in[1];   // [8,2,64,64]
    float* out = (float*)d_out;                // [8,32,64,64] fp32

    float4* params = (float4*)d_ws;                                    // 512 KB
    float*  xt     = (float*)((char*)d_ws + NB * HW * sizeof(float4)); // 4 MB

    prep_kernel<<<dim3(NB * 16, 2), dim3(256), 0, stream>>>(x, of, params, xt);
    gather_kernel<<<dim3(64, 2, NB), dim3(256), 0, stream>>>(params, (const float4*)xt, out);
}

// Round 13
// 68.542 us; speedup vs baseline: 1.0694x; 1.0324x over previous
//
#include <hip/hip_runtime.h>
#include <hip/hip_fp16.h>
#include <math.h>

#define HW    4096
#define NC    32
#define NB    8
#define TINV  10.0f            // 1/TEMP
#define RWIN  8                // window radius; missed sources need |of|>5.5
#define WDIM  (8 + 2 * RWIN)   // 24
#define RCUT  2.0f             // rect cut; error impact unmeasurable at R12

// ws layout: params (float4 per b*HW) then xt2 (__half2 x, [b][j][16 ch-pairs])

__device__ __forceinline__ __half2 u32_as_h2(unsigned int u) {
    union { unsigned int u; __half2 h; } c; c.u = u; return c.h;
}

// grid (NB*16, 2): y half 0 -> params + ch 0-15; y=1 -> ch 16-31
__global__ __launch_bounds__(256) void prep_kernel(
    const float* __restrict__ x, const float* __restrict__ of,
    float4* __restrict__ params, __half2* __restrict__ xt2)
{
    __shared__ float tile[16][257];
    int bx   = blockIdx.x;
    int half = blockIdx.y;
    int b    = bx >> 4;
    int j0   = (bx & 15) << 8;
    int t    = threadIdx.x;
    int j    = j0 + t;
    int ch0  = half << 4;

    if (half == 0) {
        float oy = (float)(j >> 6) + of[(b * 2 + 0) * HW + j];
        float ox = (float)(j & 63) + of[(b * 2 + 1) * HW + j];
        // truncated denominators: omitted terms < e^-25 relative
        int cy0 = min(max((int)floorf(oy), 0), 63);
        int cx0 = min(max((int)floorf(ox), 0), 63);
        float Dy = 0.f, Dx = 0.f;
        #pragma unroll
        for (int d = -3; d <= 3; ++d) {
            int iy = cy0 + d, ix = cx0 + d;
            if ((unsigned)iy < 64u) Dy += __expf(-TINV * fabsf(oy - (float)iy));
            if ((unsigned)ix < 64u) Dx += __expf(-TINV * fabsf(ox - (float)ix));
        }
        params[(b << 12) + j] = make_float4(oy, ox, 1.f / Dy, 1.f / Dx);
    }

    // 16-channel half-transpose; read side coalesced, store as half2
    #pragma unroll
    for (int c = 0; c < 16; ++c)
        tile[c][t] = x[((b * NC + ch0 + c) << 12) + j];
    __syncthreads();
    #pragma unroll
    for (int k = 0; k < 8; ++k) {
        int o   = k * 256 + t;            // 2048 half2 per block
        int jj  = o >> 3, pr = o & 7;     // pr-th ch-pair of this half
        xt2[((size_t)((b << 12) + j0 + jj)) * 16 + (half << 3) + pr] =
            __floats2half2_rn(tile[2 * pr][jj], tile[2 * pr + 1][jj]);
    }
}

// grid: (64 tiles, 2 channel-halves, 8 batches); 16 channels per block
__global__ __launch_bounds__(256) void gather_kernel(
    const float4* __restrict__ params, const unsigned int* __restrict__ xtu,
    float* __restrict__ out)
{
    __shared__ float4 wp[4][64];          //  4 KB  survivor params
    __shared__ int    sj[4][64];          //  1 KB  survivor source idx
    __shared__ float  pool[4 * 64 * 17];  // 17 KB: XS (u32 staging) then red

    const int b    = blockIdx.z;
    const int h    = blockIdx.y;          // channel half
    const int tile = blockIdx.x;
    const int ty0  = (tile >> 3) << 3;
    const int tx0  = (tile & 7) << 3;

    const int tid  = threadIdx.x;
    const int lane = tid & 63;
    const int wv   = __builtin_amdgcn_readfirstlane(tid >> 6);

    const float iy = (float)(ty0 + (lane >> 3));
    const float ix = (float)(tx0 + (lane & 7));

    __half2 acc8[8];
    #pragma unroll
    for (int c = 0; c < 8; ++c) acc8[c] = __floats2half2_rn(0.f, 0.f);

    const float4*       pb = params + (b << 12);
    const unsigned int* xb = xtu + (size_t)(b << 12) * 16 + (h << 3); // 8 u32/src

    const int srow = lane >> 5;           // 2 window rows x 32 cols per round
    const int scol = lane & 31;

    unsigned int* XSu = (unsigned int*)pool;   // [wv*64+s]*8 u32 per survivor

    for (int r = 0; r < 3; ++r) {
        // ---- screen 64 candidates ----
        int ry = wv + srow * 4 + r * 8;   // all 24 rows over 4 waves
        int jy = ty0 - RWIN + ry;
        int jx = tx0 - RWIN + scol;
        bool valid = ((unsigned)jy < 64u) && ((unsigned)jx < 64u) && (scol < WDIM);
        int j = (jy << 6) + jx;
        float4 p = pb[valid ? j : 0];
        float cy = fminf(fmaxf(p.x, 0.f), 63.f);
        float cx = fminf(fmaxf(p.y, 0.f), 63.f);
        float dyr = fmaxf(fmaxf((float)ty0 - cy, cy - ((float)ty0 + 7.f)), 0.f);
        float dxr = fmaxf(fmaxf((float)tx0 - cx, cx - ((float)tx0 + 7.f)), 0.f);
        bool pred = valid && (dyr + dxr < RCUT);

        unsigned long long m = __ballot(pred);
        int cnt = __popcll(m);
        if (pred) {
            int pos = __builtin_amdgcn_mbcnt_hi((unsigned)(m >> 32),
                      __builtin_amdgcn_mbcnt_lo((unsigned)m, 0u));
            wp[wv][pos] = p;
            sj[wv][pos] = j;
        }

        // ---- stage survivors' x (half2): 2 lanes x 16 B, 32 surv/pass ----
        for (int m4 = 0; m4 < cnt; m4 += 32) {
            int s = m4 + (lane >> 1);
            if (s < cnt) {
                int jj = sj[wv][s];
                const uint4* src = (const uint4*)(xb + jj * 16 + ((lane & 1) << 2));
                *(uint4*)&XSu[(((wv << 6) + s) << 3) + ((lane & 1) << 2)] = *src;
            }
        }

        // ---- FMA over survivors, 2-wide, packed fp16 ----
        for (int k = 0; k < cnt; k += 2) {
            int i1 = min(k + 1, cnt - 1);
            float4 p0 = wp[wv][k], p1 = wp[wv][i1];
            const uint4* x0 = (const uint4*)&XSu[((wv << 6) + k)  << 3];
            const uint4* x1 = (const uint4*)&XSu[((wv << 6) + i1) << 3];
            uint4 A0 = x0[0], A1 = x0[1];
            uint4 B0 = x1[0], B1 = x1[1];

            // per-dim normalize before product (fp32 overflow safety for OOB)
            float g0 = (__expf(-TINV * fabsf(p0.x - iy)) * p0.z)
                     * (__expf(-TINV * fabsf(p0.y - ix)) * p0.w);
            float g1 = (__expf(-TINV * fabsf(p1.x - iy)) * p1.z)
                     * (__expf(-TINV * fabsf(p1.y - ix)) * p1.w);
            g1 = (k + 1 < cnt) ? g1 : 0.f;
            __half2 hg0 = __float2half2_rn(g0);
            __half2 hg1 = __float2half2_rn(g1);

            acc8[0] = __hfma2(hg0, u32_as_h2(A0.x), acc8[0]);
            acc8[1] = __hfma2(hg0, u32_as_h2(A0.y), acc8[1]);
            acc8[2] = __hfma2(hg0, u32_as_h2(A0.z), acc8[2]);
            acc8[3] = __hfma2(hg0, u32_as_h2(A0.w), acc8[3]);
            acc8[4] = __hfma2(hg0, u32_as_h2(A1.x), acc8[4]);
            acc8[5] = __hfma2(hg0, u32_as_h2(A1.y), acc8[5]);
            acc8[6] = __hfma2(hg0, u32_as_h2(A1.z), acc8[6]);
            acc8[7] = __hfma2(hg0, u32_as_h2(A1.w), acc8[7]);

            acc8[0] = __hfma2(hg1, u32_as_h2(B0.x), acc8[0]);
            acc8[1] = __hfma2(hg1, u32_as_h2(B0.y), acc8[1]);
            acc8[2] = __hfma2(hg1, u32_as_h2(B0.z), acc8[2]);
            acc8[3] = __hfma2(hg1, u32_as_h2(B0.w), acc8[3]);
            acc8[4] = __hfma2(hg1, u32_as_h2(B1.x), acc8[4]);
            acc8[5] = __hfma2(hg1, u32_as_h2(B1.y), acc8[5]);
            acc8[6] = __hfma2(hg1, u32_as_h2(B1.z), acc8[6]);
            acc8[7] = __hfma2(hg1, u32_as_h2(B1.w), acc8[7]);
        }
    }

    // ---- unpack to fp32, cross-wave reduction (red overlays XS) ----
    float acc[16];
    #pragma unroll
    for (int u = 0; u < 8; ++u) {
        float2 f = __half22float2(acc8[u]);
        acc[2 * u]     = f.x;
        acc[2 * u + 1] = f.y;
    }
    __syncthreads();
    float* red = pool;                    // stride 17 -> at most 2-way = free
    float* myred = red + ((wv << 6) + lane) * 17;
    #pragma unroll
    for (int c = 0; c < 16; ++c) myred[c] = acc[c];
    __syncthreads();

    int c   = tid >> 4;                   // 0..15
    int t16 = tid & 15;
    #pragma unroll
    for (int k = 0; k < 4; ++k) {
        int t = t16 + 16 * k;
        float s = red[(0 * 64 + t) * 17 + c]
                + red[(1 * 64 + t) * 17 + c]
                + red[(2 * 64 + t) * 17 + c]
                + red[(3 * 64 + t) * 17 + c];
        int ch = h * 16 + c;
        out[(((b << 5) + ch) << 12) + (ty0 + (t >> 3)) * 64 + (tx0 + (t & 7))] = s;
    }
}

extern "C" void kernel_launch(void* const* d_in, const int* in_sizes, int n_in,
                              void* d_out, int out_size, void* d_ws, size_t ws_size,
                              hipStream_t stream) {
    const float* x  = (const float*)d_in[0];   // [8,32,64,64]
    const float* of = (const float*)d_in[1];   // [8,2,64,64]
    float* out = (float*)d_out;                // [8,32,64,64] fp32

    float4*  params = (float4*)d_ws;                                     // 512 KB
    __half2* xt2    = (__half2*)((char*)d_ws + NB * HW * sizeof(float4)); // 2 MB

    prep_kernel<<<dim3(NB * 16, 2), dim3(256), 0, stream>>>(x, of, params, xt2);
    gather_kernel<<<dim3(64, 2, NB), dim3(256), 0, stream>>>(
        params, (const unsigned int*)xt2, out);
}

// Round 14
// 68.499 us; speedup vs baseline: 1.0701x; 1.0006x over previous
//
#include <hip/hip_runtime.h>
#include <hip/hip_fp16.h>
#include <math.h>

#define HW    4096
#define NC    32
#define NB    8
#define TINV  10.0f            // 1/TEMP
#define RWIN  8                // window radius; missed sources need |of|>5.5
#define WDIM  (8 + 2 * RWIN)   // 24
#define RCUT  2.0f             // rect cut; error impact unmeasurable at R12

// ws layout: params (float4 per b*HW) then xt2 (__half2 x, [b][j][16 ch-pairs])

__device__ __forceinline__ __half2 u32_as_h2(unsigned int u) {
    union { unsigned int u; __half2 h; } c; c.u = u; return c.h;
}
__device__ __forceinline__ unsigned int h2_as_u32(__half2 h) {
    union { __half2 h; unsigned int u; } c; c.h = h; return c.u;
}

// grid (NB*16, 2): y half 0 -> params + ch 0-15; y=1 -> ch 16-31
__global__ __launch_bounds__(256) void prep_kernel(
    const float* __restrict__ x, const float* __restrict__ of,
    float4* __restrict__ params, __half2* __restrict__ xt2)
{
    __shared__ float tile[16][257];
    int bx   = blockIdx.x;
    int half = blockIdx.y;
    int b    = bx >> 4;
    int j0   = (bx & 15) << 8;
    int t    = threadIdx.x;
    int j    = j0 + t;
    int ch0  = half << 4;

    if (half == 0) {
        float oy = (float)(j >> 6) + of[(b * 2 + 0) * HW + j];
        float ox = (float)(j & 63) + of[(b * 2 + 1) * HW + j];
        // truncated denominators: omitted terms < e^-25 relative
        int cy0 = min(max((int)floorf(oy), 0), 63);
        int cx0 = min(max((int)floorf(ox), 0), 63);
        float Dy = 0.f, Dx = 0.f;
        #pragma unroll
        for (int d = -3; d <= 3; ++d) {
            int iy = cy0 + d, ix = cx0 + d;
            if ((unsigned)iy < 64u) Dy += __expf(-TINV * fabsf(oy - (float)iy));
            if ((unsigned)ix < 64u) Dx += __expf(-TINV * fabsf(ox - (float)ix));
        }
        params[(b << 12) + j] = make_float4(oy, ox, 1.f / Dy, 1.f / Dx);
    }

    // 16-channel half-transpose; read side coalesced, store as half2
    #pragma unroll
    for (int c = 0; c < 16; ++c)
        tile[c][t] = x[((b * NC + ch0 + c) << 12) + j];
    __syncthreads();
    #pragma unroll
    for (int k = 0; k < 8; ++k) {
        int o   = k * 256 + t;            // 2048 half2 per block
        int jj  = o >> 3, pr = o & 7;     // pr-th ch-pair of this half
        xt2[((size_t)((b << 12) + j0 + jj)) * 16 + (half << 3) + pr] =
            __floats2half2_rn(tile[2 * pr][jj], tile[2 * pr + 1][jj]);
    }
}

// grid: (64 tiles, 2 channel-halves, 8 batches); 16 channels per block
__global__ __launch_bounds__(256) void gather_kernel(
    const float4* __restrict__ params, const unsigned int* __restrict__ xtu,
    float* __restrict__ out)
{
    __shared__ float4       wp[4][65];    // survivor params + dummy slot
    __shared__ int          sj[4][64];    // survivor source idx
    __shared__ unsigned int pool[4 * 64 * 9];  // 9 KB: XSu staging, then redu

    const int b    = blockIdx.z;
    const int h    = blockIdx.y;          // channel half
    const int tile = blockIdx.x;
    const int ty0  = (tile >> 3) << 3;
    const int tx0  = (tile & 7) << 3;

    const int tid  = threadIdx.x;
    const int lane = tid & 63;
    const int wv   = __builtin_amdgcn_readfirstlane(tid >> 6);

    const float iy = (float)(ty0 + (lane >> 3));
    const float ix = (float)(tx0 + (lane & 7));

    __half2 acc8[8];
    #pragma unroll
    for (int c = 0; c < 8; ++c) acc8[c] = __floats2half2_rn(0.f, 0.f);

    const float4*       pb = params + (b << 12);
    const unsigned int* xb = xtu + (size_t)(b << 12) * 16 + (h << 3); // 8 u32/src

    const int srow = lane >> 5;           // 2 window rows x 32 cols per round
    const int scol = lane & 31;

    unsigned int* XSu = pool;             // [wv*64+s]*8 u32 per survivor

    for (int r = 0; r < 3; ++r) {
        // ---- screen 64 candidates ----
        int ry = wv + srow * 4 + r * 8;   // all 24 rows over 4 waves
        int jy = ty0 - RWIN + ry;
        int jx = tx0 - RWIN + scol;
        bool valid = ((unsigned)jy < 64u) && ((unsigned)jx < 64u) && (scol < WDIM);
        int j = (jy << 6) + jx;
        float4 p = pb[valid ? j : 0];
        float cy = fminf(fmaxf(p.x, 0.f), 63.f);
        float cx = fminf(fmaxf(p.y, 0.f), 63.f);
        float dyr = fmaxf(fmaxf((float)ty0 - cy, cy - ((float)ty0 + 7.f)), 0.f);
        float dxr = fmaxf(fmaxf((float)tx0 - cx, cx - ((float)tx0 + 7.f)), 0.f);
        bool pred = valid && (dyr + dxr < RCUT);

        unsigned long long m = __ballot(pred);
        int cnt = __popcll(m);
        if (pred) {
            int pos = __builtin_amdgcn_mbcnt_hi((unsigned)(m >> 32),
                      __builtin_amdgcn_mbcnt_lo((unsigned)m, 0u));
            wp[wv][pos] = p;
            sj[wv][pos] = j;
        }
        // zero-weight dummy pads odd counts: p.z==0 -> g==0 exactly
        if (lane == cnt) wp[wv][cnt] = make_float4(1.f, 1.f, 0.f, 0.f);
        int cntp = cnt + (cnt & 1);       // even trip count, no tail selects

        // ---- stage survivors' x (half2): 2 lanes x 16 B, 32 surv/pass ----
        // (dummy slot staged with survivor 0's data: finite, weight 0)
        for (int m4 = 0; m4 < cntp; m4 += 32) {
            int s = m4 + (lane >> 1);
            if (s < cntp) {
                int jj = sj[wv][min(s, cnt - 1)];
                const uint4* src = (const uint4*)(xb + jj * 16 + ((lane & 1) << 2));
                *(uint4*)&XSu[(((wv << 6) + s) << 3) + ((lane & 1) << 2)] = *src;
            }
        }

        // ---- FMA over survivors, 2-wide, packed fp16, branchless body ----
        for (int k = 0; k < cntp; k += 2) {
            float4 p0 = wp[wv][k], p1 = wp[wv][k + 1];
            const uint4* x0 = (const uint4*)&XSu[((wv << 6) + k)     << 3];
            const uint4* x1 = (const uint4*)&XSu[((wv << 6) + k + 1) << 3];
            uint4 A0 = x0[0], A1 = x0[1];
            uint4 B0 = x1[0], B1 = x1[1];

            // per-dim normalize before product (fp32 overflow safety for OOB)
            float g0 = (__expf(-TINV * fabsf(p0.x - iy)) * p0.z)
                     * (__expf(-TINV * fabsf(p0.y - ix)) * p0.w);
            float g1 = (__expf(-TINV * fabsf(p1.x - iy)) * p1.z)
                     * (__expf(-TINV * fabsf(p1.y - ix)) * p1.w);
            __half2 hg0 = __float2half2_rn(g0);
            __half2 hg1 = __float2half2_rn(g1);

            acc8[0] = __hfma2(hg0, u32_as_h2(A0.x), acc8[0]);
            acc8[1] = __hfma2(hg0, u32_as_h2(A0.y), acc8[1]);
            acc8[2] = __hfma2(hg0, u32_as_h2(A0.z), acc8[2]);
            acc8[3] = __hfma2(hg0, u32_as_h2(A0.w), acc8[3]);
            acc8[4] = __hfma2(hg0, u32_as_h2(A1.x), acc8[4]);
            acc8[5] = __hfma2(hg0, u32_as_h2(A1.y), acc8[5]);
            acc8[6] = __hfma2(hg0, u32_as_h2(A1.z), acc8[6]);
            acc8[7] = __hfma2(hg0, u32_as_h2(A1.w), acc8[7]);

            acc8[0] = __hfma2(hg1, u32_as_h2(B0.x), acc8[0]);
            acc8[1] = __hfma2(hg1, u32_as_h2(B0.y), acc8[1]);
            acc8[2] = __hfma2(hg1, u32_as_h2(B0.z), acc8[2]);
            acc8[3] = __hfma2(hg1, u32_as_h2(B0.w), acc8[3]);
            acc8[4] = __hfma2(hg1, u32_as_h2(B1.x), acc8[4]);
            acc8[5] = __hfma2(hg1, u32_as_h2(B1.y), acc8[5]);
            acc8[6] = __hfma2(hg1, u32_as_h2(B1.z), acc8[6]);
            acc8[7] = __hfma2(hg1, u32_as_h2(B1.w), acc8[7]);
        }
    }

    // ---- cross-wave reduction, PACKED half2 (combine in fp32 after unpack);
    //      redu overlays XSu after barrier; stride 9 u32 -> conflict-free ----
    __syncthreads();
    unsigned int* redu = pool;
    unsigned int* myr  = redu + ((wv << 6) + lane) * 9;
    #pragma unroll
    for (int c = 0; c < 8; ++c) myr[c] = h2_as_u32(acc8[c]);
    __syncthreads();

    int c2  = tid >> 5;                   // ch-pair 0..7
    int t32 = tid & 31;                   // target within tile (lo)
    #pragma unroll
    for (int k = 0; k < 2; ++k) {
        int t = t32 + 32 * k;
        float sx = 0.f, sy = 0.f;
        #pragma unroll
        for (int w = 0; w < 4; ++w) {
            float2 f = __half22float2(u32_as_h2(redu[((w << 6) + t) * 9 + c2]));
            sx += f.x; sy += f.y;
        }
        int ch   = h * 16 + 2 * c2;
        int base = (((b << 5) + ch) << 12) + (ty0 + (t >> 3)) * 64 + (tx0 + (t & 7));
        out[base]        = sx;
        out[base + 4096] = sy;
    }
}

extern "C" void kernel_launch(void* const* d_in, const int* in_sizes, int n_in,
                              void* d_out, int out_size, void* d_ws, size_t ws_size,
                              hipStream_t stream) {
    const float* x  = (const float*)d_in[0];   // [8,32,64,64]
    const float* of = (const float*)d_in[1];   // [8,2,64,64]
    float* out = (float*)d_out;                // [8,32,64,64] fp32

    float4*  params = (float4*)d_ws;                                     // 512 KB
    __half2* xt2    = (__half2*)((char*)d_ws + NB * HW * sizeof(float4)); // 2 MB

    prep_kernel<<<dim3(NB * 16, 2), dim3(256), 0, stream>>>(x, of, params, xt2);
    gather_kernel<<<dim3(64, 2, NB), dim3(256), 0, stream>>>(
        params, (const unsigned int*)xt2, out);
}